// Round 3
// baseline (200.524 us; speedup 1.0000x reference)
//
#include <hip/hip_runtime.h>
#include <cstdint>

#define BN 4
#define CIN 256
#define HALFC 128
#define HW 4096
#define SPLIT 4
#define JT 64
#define JITERS (HW / SPLIT / JT)   // 16

typedef float  floatx4 __attribute__((ext_vector_type(4)));
typedef short  shortx8 __attribute__((ext_vector_type(8)));

#if __has_builtin(__builtin_amdgcn_exp2f)
#define EXP2F(x) __builtin_amdgcn_exp2f(x)
#else
#define EXP2F(x) exp2f(x)
#endif
#define L2E 1.44269504088896f

__device__ __forceinline__ unsigned short f2bf(float f) {
  unsigned u = __float_as_uint(f);
  u += 0x7FFFu + ((u >> 16) & 1u);   // round-to-nearest-even
  return (unsigned short)(u >> 16);
}

__device__ __forceinline__ void async16(const void* g, void* l) {
  __builtin_amdgcn_global_load_lds((const __attribute__((address_space(1))) void*)g,
                                   (__attribute__((address_space(3))) void*)l, 16, 0, 0);
}

// ---------------- K0: cast/transpose x -> Xt [b][px][ci] bf16; W -> Wh bf16 -----------
__global__ __launch_bounds__(256) void k_split(const float* __restrict__ x,
    const float* __restrict__ w1, const float* __restrict__ w2,
    const float* __restrict__ w3, unsigned short* __restrict__ Xth,
    unsigned short* __restrict__ Wh) {
  __shared__ float smf[64 * 65];
  int bid = blockIdx.x;
  int t = threadIdx.x;
  if (bid < 1024) {
    int b = bid >> 8, rem = bid & 255;
    int cit = rem >> 6, pxt = rem & 63;     // ci tile (4), px tile (64)
    const float* src = x + (size_t)b * 1048576 + (size_t)(cit * 64) * HW + pxt * 64;
#pragma unroll
    for (int k = 0; k < 16; k++) {
      int idx = k * 256 + t;
      int r = idx >> 6, c = idx & 63;
      smf[r * 65 + c] = src[(size_t)r * HW + c];
    }
    __syncthreads();
    int prow = t >> 2, seg = t & 3;
    union { unsigned short us[16]; uint4 v[2]; } oh;
#pragma unroll
    for (int u = 0; u < 16; u++)
      oh.us[u] = f2bf(smf[(seg * 16 + u) * 65 + prow]);
    size_t dst = (size_t)b * 1048576 + (size_t)(pxt * 64 + prow) * 256 + cit * 64 + seg * 16;
    *(uint4*)(Xth + dst) = oh.v[0];
    *(uint4*)(Xth + dst + 8) = oh.v[1];
  } else {
    int bw = bid - 1024;                    // 0..11, each block 8192 elems
    int f0 = bw * 8192 + t * 32;
    const float* wsrc;
    int fo;
    if (f0 < 32768)      { wsrc = w1; fo = f0; }
    else if (f0 < 65536) { wsrc = w2; fo = f0 - 32768; }
    else                 { wsrc = w3; fo = f0 - 65536; }
    union { unsigned short us[32]; uint4 v[4]; } oh;
#pragma unroll
    for (int u = 0; u < 32; u++) oh.us[u] = f2bf(wsrc[fo + u]);
#pragma unroll
    for (int k = 0; k < 4; k++) *((uint4*)(Wh + f0) + k) = oh.v[k];
  }
}

// ---------------- K1: MFMA projection (bf16, fp32 acc) ---------------------------------
__global__ __launch_bounds__(256) void k_projM(const unsigned short* __restrict__ Xth,
    const unsigned short* __restrict__ Wh, unsigned short* __restrict__ Q,
    unsigned short* __restrict__ Kt, unsigned short* __restrict__ n3) {
  __shared__ unsigned short XhS[4096];   // [128 px][32 ci] fragment order, 8 KB
  __shared__ unsigned short ES[9216];    // epilogue stage
  int bid = blockIdx.x;
  int pxt = bid & 31;
  int ct = bid >> 5;                     // b*6 + cot
  int b = ct / 6, cot = ct % 6;
  int px0 = pxt * 128, co0 = cot * 64;
  int t = threadIdx.x;
  int w = t >> 6, lane = t & 63, l16 = lane & 15, quad = lane >> 4;

  int myco = co0 + w * 16 + l16;
  shortx8 whf[8];
#pragma unroll
  for (int s = 0; s < 8; s++)
    whf[s] = *(const shortx8*)(Wh + (size_t)myco * 256 + s * 32 + quad * 8);
  floatx4 acc[8];
  floatx4 zf = {0.f, 0.f, 0.f, 0.f};
#pragma unroll
  for (int mt = 0; mt < 8; mt++) acc[mt] = zf;
  const unsigned short* XhB = Xth + (size_t)b * 1048576;
  int k8 = lane >> 4, pxm = lane & 15;

#pragma unroll
  for (int s = 0; s < 8; s++) {
    __syncthreads();
#pragma unroll
    for (int c2 = 0; c2 < 2; c2++) {     // stage fragment-order; lane L -> slot L*16
      int px = px0 + (c2 * 4 + w) * 16 + pxm;
      async16(XhB + (size_t)px * 256 + s * 32 + k8 * 8, (char*)XhS + c2 * 4096 + w * 1024);
    }
    __syncthreads();
#pragma unroll
    for (int mt = 0; mt < 8; mt++) {
      shortx8 ah = *(const shortx8*)((const char*)XhS + mt * 1024 + lane * 16);
      acc[mt] = __builtin_amdgcn_mfma_f32_16x16x32_bf16(ah, whf[s], acc[mt], 0, 0, 0);
    }
  }
  __syncthreads();
  // D layout: element [px = mt*16 + quad*4 + rr][co_l = w*16 + l16]
  if (cot < 2 || cot >= 4) {             // Q / n3: stage [co][px]
    int co_l = w * 16 + l16;
#pragma unroll
    for (int mt = 0; mt < 8; mt++) {
      int px = mt * 16 + quad * 4;
      unsigned lo = (unsigned)f2bf(acc[mt][0]) | ((unsigned)f2bf(acc[mt][1]) << 16);
      unsigned hi = (unsigned)f2bf(acc[mt][2]) | ((unsigned)f2bf(acc[mt][3]) << 16);
      *(uint2*)(ES + co_l * 136 + px) = make_uint2(lo, hi);
    }
    __syncthreads();
    int cr = t >> 2, seg = t & 3;
    unsigned short* dstb = (cot < 2)
        ? Q  + (size_t)b * 524288 + (size_t)(co0 + cr) * HW
        : n3 + (size_t)b * 524288 + (size_t)(co0 - 256 + cr) * HW;
#pragma unroll
    for (int k2 = 0; k2 < 4; k2++) {
      uint4 v = *(const uint4*)(ES + cr * 136 + seg * 32 + k2 * 8);
      *(uint4*)(dstb + px0 + seg * 32 + k2 * 8) = v;
    }
  } else {                               // Kt: stage [px][co]
#pragma unroll
    for (int mt = 0; mt < 8; mt++)
#pragma unroll
      for (int rr = 0; rr < 4; rr++) {
        int px = mt * 16 + quad * 4 + rr;
        ES[px * 72 + w * 16 + l16] = f2bf(acc[mt][rr]);
      }
    __syncthreads();
    int ch0 = co0 - 128;
#pragma unroll
    for (int it = 0; it < 4; it++) {
      int cid = it * 256 + t;
      int px = cid >> 3, c8 = cid & 7;
      uint4 v = *(const uint4*)(ES + px * 72 + c8 * 8);
      *(uint4*)(Kt + (size_t)b * 524288 + (size_t)(px0 + px) * 128 + ch0 + c8 * 8) = v;
    }
  }
}

// ---------------- K2: VtF: V in wave-fragment order for direct coalesced PV loads ------
// slot s = (nt*2+kt)*64 + quad*16 + l16 holds V[j = jt*64+kt*32+quad*8+e][c = nt*16+l16]
__global__ __launch_bounds__(256) void k_layoutVF(const unsigned short* __restrict__ n3,
    unsigned short* __restrict__ VtF) {
  __shared__ unsigned short sm[8192];
  int bid = blockIdx.x;                  // 256 = b(4) x jt(64)
  int b = bid >> 6, jt = bid & 63;
  int t = threadIdx.x;
  const unsigned short* src = n3 + (size_t)b * 524288 + (size_t)(jt * 2) * 4096;
#pragma unroll
  for (int k = 0; k < 32; k++) sm[k * 256 + t] = src[k * 256 + t];
  __syncthreads();
  unsigned short* dst = VtF + (size_t)b * 524288 + (size_t)jt * 8192;
#pragma unroll
  for (int k = 0; k < 4; k++) {
    int s = k * 256 + t;
    int nt = s >> 7, kt = (s >> 6) & 1, quad = (s >> 4) & 3, l16 = s & 15;
    union { unsigned short us[8]; uint4 v; } o;
#pragma unroll
    for (int e = 0; e < 8; e++)
      o.us[e] = sm[kt * 4096 + (quad * 8 + e) * 128 + nt * 16 + l16];
    *(uint4*)(dst + s * 8) = o.v;
  }
}

// ---------------- K3: fused flash attention (T15 deferred-PV pipeline) ------------------
// Not a pipe-bound kernel (all pipes <30% in r2): bound by the per-iter serial chain
// QK->softmax->pack->PV with 2 lockstep waves/SIMD. Fix: defer PV one iteration.
// Iter t issues PV(t-1) (operands ready: P(t-1) in PS[dbuf], vf(t-1) in regs) back-to-back
// with QK(t) -> 64 MFMA in flight, softmax(t) VALU overlaps the MFMA drain.
// Math identical: O = (O + P(t-1)V(t-1)) * alpha(t), epilogue adds P(15)V(15).
// vf double-buffered via two NAMES (unroll-by-2), never runtime-indexed (no scratch).
// PS double-buffered: LDS 32(KtS)+32(PS) = 64KB -> still 2 blocks/CU.
__device__ __forceinline__ void flash_body(int it, bool haspv,
    shortx8 (&vfc)[8][2], shortx8 (&vfp)[8][2],
    shortx8 (&qf)[2][4], floatx4 (&O)[2][8],
    float (&m_i)[2], float (&l_i)[2],
    const unsigned short* vB, const unsigned short* kbase,
    unsigned short* KtS, char* Pw, int w, int lane, int l16, int quad) {
  int cur = it & 1, nxt = cur ^ 1;
  floatx4 zf = {0.f, 0.f, 0.f, 0.f};
  // barrier A: all waves done QK(it-1) -> KtS[nxt] free for prefetch
  __asm__ __volatile__("s_barrier" ::: "memory");
  // vf loads for tile it (global->reg, coalesced). Issued BEFORE prefetch (vmcnt order).
  {
    const unsigned short* vt = vB + (size_t)it * 8192;
#pragma unroll
    for (int nt = 0; nt < 8; nt++)
#pragma unroll
      for (int kt = 0; kt < 2; kt++)
        vfc[nt][kt] = *(const shortx8*)(vt + (nt * 2 + kt) * 512);
  }
  if (it + 1 < JITERS) {
    const unsigned short* kp = kbase + (size_t)(it + 1) * 8192;
#pragma unroll
    for (int c4 = 0; c4 < 4; c4++)
      async16(kp + c4 * 2048, (char*)KtS + nxt * 16384 + c4 * 4096 + w * 1024);
    // newest 20 = vfc(16) + pfn(4); drains pf(it) AND vf(it-1) (needed by PV below)
    __asm__ __volatile__("s_waitcnt vmcnt(20)" ::: "memory");
  } else {
    __asm__ __volatile__("s_waitcnt vmcnt(16)" ::: "memory");
  }
  // barrier B: all waves' tile-it Kt staging landed
  __asm__ __volatile__("s_barrier" ::: "memory");

  // ---- PV(it-1): independent of QK(it); fills the MFMA pipe while QK's ds_reads fly ----
  if (haspv) {
    __asm__ __volatile__("s_waitcnt lgkmcnt(0)" ::: "memory");  // pack(it-1) visible
    const char* Pr = Pw + ((it ^ 1) & 1) * 4096;
    __builtin_amdgcn_s_setprio(1);
#pragma unroll
    for (int kt = 0; kt < 2; kt++) {
      shortx8 pf0 = *(const shortx8*)(Pr + kt * 1024 + lane * 16);
      shortx8 pf1 = *(const shortx8*)(Pr + 2048 + kt * 1024 + lane * 16);
#pragma unroll
      for (int nt = 0; nt < 8; nt++) {
        O[0][nt] = __builtin_amdgcn_mfma_f32_16x16x32_bf16(pf0, vfp[nt][kt], O[0][nt], 0, 0, 0);
        O[1][nt] = __builtin_amdgcn_mfma_f32_16x16x32_bf16(pf1, vfp[nt][kt], O[1][nt], 0, 0, 0);
      }
    }
    __builtin_amdgcn_s_setprio(0);
  }

  const char* kc = (const char*)KtS + cur * 16384;
  // ---- QK: S^T[j][i]; each af feeds both i-groups ----
  floatx4 S[2][4];
#pragma unroll
  for (int ig = 0; ig < 2; ig++)
#pragma unroll
    for (int mt = 0; mt < 4; mt++) S[ig][mt] = zf;
  __builtin_amdgcn_s_setprio(1);
#pragma unroll
  for (int mt = 0; mt < 4; mt++) {
#pragma unroll
    for (int ks = 0; ks < 4; ks++) {
      shortx8 af = *(const shortx8*)(kc + mt * 4096 + ks * 1024 + lane * 16);
      S[0][mt] = __builtin_amdgcn_mfma_f32_16x16x32_bf16(af, qf[0][ks], S[0][mt], 0, 0, 0);
      S[1][mt] = __builtin_amdgcn_mfma_f32_16x16x32_bf16(af, qf[1][ks], S[1][mt], 0, 0, 0);
    }
  }
  __builtin_amdgcn_s_setprio(0);

  // ---- max phase (tree, depth 4); overlaps the PV/QK MFMA drain ----
  float tmax[2];
#pragma unroll
  for (int ig = 0; ig < 2; ig++) {
    float a0 = fmaxf(fmaxf(S[ig][0][0], S[ig][0][1]), fmaxf(S[ig][0][2], S[ig][0][3]));
    float a1 = fmaxf(fmaxf(S[ig][1][0], S[ig][1][1]), fmaxf(S[ig][1][2], S[ig][1][3]));
    float a2 = fmaxf(fmaxf(S[ig][2][0], S[ig][2][1]), fmaxf(S[ig][2][2], S[ig][2][3]));
    float a3 = fmaxf(fmaxf(S[ig][3][0], S[ig][3][1]), fmaxf(S[ig][3][2], S[ig][3][3]));
    float tm = fmaxf(fmaxf(a0, a1), fmaxf(a2, a3));
    tm = fmaxf(tm, __shfl_xor(tm, 16));
    tm = fmaxf(tm, __shfl_xor(tm, 32));
    tmax[ig] = tm;
  }
  // ---- T13 defer-max: only touch m/O when some row grew by > 8 nats ----
  // (O-rescale reads O -> HW waits for PV(it-1) accumulation to retire; correct order:
  //  PV(it-1) contributes at scale m(it-1), THEN alpha(it) rescales.)
  float alpha[2] = {1.f, 1.f};
  if (__ballot(tmax[0] > m_i[0] + 8.f || tmax[1] > m_i[1] + 8.f)) {
#pragma unroll
    for (int ig = 0; ig < 2; ig++) {
      float mn = fmaxf(m_i[ig], tmax[ig]);
      alpha[ig] = EXP2F((m_i[ig] - mn) * L2E);
      m_i[ig] = mn;
      float ar[4];
#pragma unroll
      for (int rr = 0; rr < 4; rr++) ar[rr] = __shfl(alpha[ig], quad * 4 + rr);
#pragma unroll
      for (int nt = 0; nt < 8; nt++)
#pragma unroll
        for (int rr = 0; rr < 4; rr++) O[ig][nt][rr] *= ar[rr];
    }
  }
  // ---- exp / sum (tree) / pack into PS[it&1]; P overwrites S ----
  char* Pd = Pw + (it & 1) * 4096;
#pragma unroll
  for (int ig = 0; ig < 2; ig++) {
    float nsc = m_i[ig] * L2E;
    float sm[4];
#pragma unroll
    for (int mt = 0; mt < 4; mt++) {
      float p0 = EXP2F(fmaf(S[ig][mt][0], L2E, -nsc));
      float p1 = EXP2F(fmaf(S[ig][mt][1], L2E, -nsc));
      float p2 = EXP2F(fmaf(S[ig][mt][2], L2E, -nsc));
      float p3 = EXP2F(fmaf(S[ig][mt][3], L2E, -nsc));
      S[ig][mt][0] = p0; S[ig][mt][1] = p1; S[ig][mt][2] = p2; S[ig][mt][3] = p3;
      sm[mt] = (p0 + p1) + (p2 + p3);
    }
    float ts = (sm[0] + sm[1]) + (sm[2] + sm[3]);
    ts += __shfl_xor(ts, 16);
    ts += __shfl_xor(ts, 32);
    l_i[ig] = l_i[ig] * alpha[ig] + ts;
    // truncating bf16 pack via v_perm (1 inst/pair)
#pragma unroll
    for (int mt = 0; mt < 4; mt++) {
      unsigned lo = __builtin_amdgcn_perm(__float_as_uint(S[ig][mt][1]),
                                          __float_as_uint(S[ig][mt][0]), 0x07060302u);
      unsigned hi = __builtin_amdgcn_perm(__float_as_uint(S[ig][mt][3]),
                                          __float_as_uint(S[ig][mt][2]), 0x07060302u);
      *(uint2*)(Pd + ig * 2048 + (mt * 2 + (quad >> 1)) * 256 + l16 * 16 + (quad & 1) * 8)
          = make_uint2(lo, hi);
    }
  }
  // pack's lgkmcnt is paid at the TOP of the next body's PV (overlaps barriers/loads)
}

__global__ __launch_bounds__(256, 2) void k_flash(const unsigned short* __restrict__ Q,
    const unsigned short* __restrict__ Kt, const unsigned short* __restrict__ VtF,
    float* __restrict__ Opart, float* __restrict__ ml) {
  __shared__ unsigned short KtS[2 * 8192];   // 2 x 16 KB
  __shared__ unsigned short PS[4 * 2 * 2048]; // 32 KB (2 x 4 KB per wave)
  int bid0 = blockIdx.x;
  int bid = (bid0 & 7) * 64 + (bid0 >> 3);   // T1: 512 blocks -> 64-block chunk per XCD
  int itile = bid & 31, sp = (bid >> 5) & 3, b = bid >> 7;
  int t = threadIdx.x;
  int w = t >> 6, lane = t & 63, l16 = lane & 15, quad = lane >> 4;
  int i0 = itile * 128;

  shortx8 qf[2][4];
#pragma unroll
  for (int ig = 0; ig < 2; ig++) {
    const unsigned short* qp = Q + ((size_t)b * HW + i0 + w * 32 + ig * 16 + l16) * 128 + quad * 8;
#pragma unroll
    for (int ks = 0; ks < 4; ks++) qf[ig][ks] = *(const shortx8*)(qp + ks * 32);
  }
  __asm__ __volatile__("s_waitcnt vmcnt(0)" ::: "memory");  // drain Q loads

  floatx4 O[2][8];
  floatx4 zf = {0.f, 0.f, 0.f, 0.f};
#pragma unroll
  for (int ig = 0; ig < 2; ig++)
#pragma unroll
    for (int nt = 0; nt < 8; nt++) O[ig][nt] = zf;
  float m_i[2] = {-1e30f, -1e30f}, l_i[2] = {0.f, 0.f};

  int ccK = w * 4 + quad;
  const unsigned short* kbase = Kt + (size_t)b * HW * 128
                              + (size_t)(sp * 1024 + l16) * 128 + ccK * 8;
  const unsigned short* vB = VtF + (size_t)b * 524288 + (size_t)(sp * 16) * 8192 + lane * 8;
  char* Pw = (char*)PS + w * 8192;

  // prologue: stage Kt tile 0 into buffer 0 (4 async16, left in flight)
#pragma unroll
  for (int c4 = 0; c4 < 4; c4++)
    async16(kbase + c4 * 2048, (char*)KtS + c4 * 4096 + w * 1024);

  shortx8 vfA[8][2], vfB[8][2];
#pragma unroll 1
  for (int it2 = 0; it2 < JITERS; it2 += 2) {
    flash_body(it2,     it2 > 0, vfA, vfB, qf, O, m_i, l_i, vB, kbase, KtS, Pw, w, lane, l16, quad);
    flash_body(it2 + 1, true,    vfB, vfA, qf, O, m_i, l_i, vB, kbase, KtS, Pw, w, lane, l16, quad);
  }
  // epilogue PV(JITERS-1): P in PS[1], V in vfB (compiler inserts the vmcnt for vfB)
  {
    __asm__ __volatile__("s_waitcnt lgkmcnt(0)" ::: "memory");
    const char* Pr = Pw + ((JITERS - 1) & 1) * 4096;
#pragma unroll
    for (int kt = 0; kt < 2; kt++) {
      shortx8 pf0 = *(const shortx8*)(Pr + kt * 1024 + lane * 16);
      shortx8 pf1 = *(const shortx8*)(Pr + 2048 + kt * 1024 + lane * 16);
#pragma unroll
      for (int nt = 0; nt < 8; nt++) {
        O[0][nt] = __builtin_amdgcn_mfma_f32_16x16x32_bf16(pf0, vfB[nt][kt], O[0][nt], 0, 0, 0);
        O[1][nt] = __builtin_amdgcn_mfma_f32_16x16x32_bf16(pf1, vfB[nt][kt], O[1][nt], 0, 0, 0);
      }
    }
  }
  // epilogue: store partial O and (m,l)
#pragma unroll
  for (int ig = 0; ig < 2; ig++) {
    float* Ob = Opart + ((size_t)(sp * 4 + b) * HW + i0 + w * 32 + ig * 16) * 128;
#pragma unroll
    for (int nt = 0; nt < 8; nt++)
#pragma unroll
      for (int rr = 0; rr < 4; rr++)
        Ob[(size_t)(quad * 4 + rr) * 128 + nt * 16 + l16] = O[ig][nt][rr];
  }
  if (quad == 0) {
    float2* mlp = (float2*)ml;
#pragma unroll
    for (int ig = 0; ig < 2; ig++)
      mlp[(size_t)(sp * 4 + b) * HW + i0 + w * 32 + ig * 16 + l16]
          = make_float2(m_i[ig], l_i[ig]);
  }
}

// ---------------- K4: merge split-j partials -> res ------------------------------------
__global__ __launch_bounds__(256) void k_merge(const float* __restrict__ Opart,
    const float* __restrict__ ml, float* __restrict__ res) {
  size_t e = (size_t)blockIdx.x * 256 + threadIdx.x;  // float4 index
  int cq = (int)(e & 31);
  int i = (int)((e >> 5) & 4095);
  int b = (int)(e >> 17);
  const float2* mlp = (const float2*)ml;
  float m[SPLIT], l[SPLIT];
  float M = -1e30f;
#pragma unroll
  for (int s = 0; s < SPLIT; s++) {
    float2 st = mlp[(size_t)(s * 4 + b) * HW + i];
    m[s] = st.x; l[s] = st.y;
    M = fmaxf(M, m[s]);
  }
  float denom = 0.f;
  float wgt[SPLIT];
#pragma unroll
  for (int s = 0; s < SPLIT; s++) {
    float ws_ = EXP2F((m[s] - M) * L2E);
    wgt[s] = ws_;
    denom += l[s] * ws_;
  }
  float inv = 1.f / denom;
  floatx4 acc = {0.f, 0.f, 0.f, 0.f};
#pragma unroll
  for (int s = 0; s < SPLIT; s++) {
    floatx4 v = *(const floatx4*)(Opart + ((size_t)(s * 4 + b) * HW + i) * 128 + cq * 4);
    acc += v * (wgt[s] * inv);
  }
  *(floatx4*)(res + e * 4) = acc;
}

// ---------------- K5: conv4 (fp32) + BN(eval) + residual ------------------------------
__global__ __launch_bounds__(256) void k_out(const float* __restrict__ res,
    const float* __restrict__ w4, const float* __restrict__ gamma,
    const float* __restrict__ beta, const float* __restrict__ rmean,
    const float* __restrict__ rvar, const float* __restrict__ x,
    float* __restrict__ out) {
  __shared__ float wt[16 * 128];
  int bid = blockIdx.x;
  int cot = bid & 15;
  int st = (bid >> 4) & 15;
  int b = bid >> 8;
  int t = threadIdx.x;
  int co0 = cot * 16;
#pragma unroll
  for (int k = 0; k < 8; k++) wt[k * 256 + t] = w4[(size_t)co0 * 128 + k * 256 + t];
  __syncthreads();
  int px = st * 256 + t;
  const float* rb = res + (size_t)b * 524288 + px;
  float acc[16];
#pragma unroll
  for (int r = 0; r < 16; r++) acc[r] = 0.f;
  for (int ci = 0; ci < 128; ci += 4) {
    float xv[4];
#pragma unroll
    for (int kk = 0; kk < 4; kk++) xv[kk] = rb[(size_t)(ci + kk) * HW];
#pragma unroll
    for (int r = 0; r < 16; r++) {
      floatx4 wv = *(const floatx4*)&wt[r * 128 + ci];
#pragma unroll
      for (int kk = 0; kk < 4; kk++) acc[r] += wv[kk] * xv[kk];
    }
  }
  const float* xb = x + ((size_t)b * 256 + co0) * HW + px;
  float* ob = out + ((size_t)b * 256 + co0) * HW + px;
#pragma unroll
  for (int r = 0; r < 16; r++) {
    int co = co0 + r;
    float g = gamma[co] * rsqrtf(rvar[co] + 1e-5f);
    float bb = beta[co] - rmean[co] * g;
    ob[(size_t)r * HW] = acc[r] * g + bb + xb[(size_t)r * HW];
  }
}

extern "C" void kernel_launch(void* const* d_in, const int* in_sizes, int n_in,
                              void* d_out, int out_size, void* d_ws, size_t ws_size,
                              hipStream_t stream) {
  const float* x     = (const float*)d_in[0];
  const float* w1    = (const float*)d_in[1];
  const float* w2    = (const float*)d_in[2];
  const float* w3    = (const float*)d_in[3];
  const float* w4    = (const float*)d_in[4];
  const float* gamma = (const float*)d_in[5];
  const float* beta  = (const float*)d_in[6];
  const float* rmean = (const float*)d_in[7];
  const float* rvar  = (const float*)d_in[8];
  float* out = (float*)d_out;
  char* ws = (char*)d_ws;

  // Opart region (32 MB) overlaps n3 / Xth (dead before k_flash runs)
  size_t off = (size_t)SPLIT * 4 * HW * 128 * 4;             // 32 MB
  float* Opart = (float*)ws;
  unsigned short* n3  = (unsigned short*)ws;                  // 4.2 MB @ 0
  unsigned short* Xth = (unsigned short*)(ws + ((size_t)8 << 20));   // 8.4 MB @ 8M
  unsigned short* Q   = (unsigned short*)(ws + off); off += (size_t)4 * HW * 128 * 2;
  unsigned short* Kt  = (unsigned short*)(ws + off); off += (size_t)4 * HW * 128 * 2;
  unsigned short* VtF = (unsigned short*)(ws + off); off += (size_t)4 * HW * 128 * 2;
  float* ml  = (float*)(ws + off); off += (size_t)SPLIT * 4 * HW * 2 * 4;
  float* res = (float*)(ws + off); off += (size_t)4 * HW * 128 * 4;
  unsigned short* Wh = (unsigned short*)(ws + off); off += (size_t)384 * 256 * 2;
  if (ws_size < off) return;

  k_split   <<<1036, 256, 0, stream>>>(x, w1, w2, w3, Xth, Wh);
  k_projM   <<<768,  256, 0, stream>>>(Xth, Wh, Q, Kt, n3);
  k_layoutVF<<<256,  256, 0, stream>>>(n3, VtF);
  k_flash   <<<512,  256, 0, stream>>>(Q, Kt, VtF, Opart, ml);
  k_merge   <<<2048, 256, 0, stream>>>(Opart, ml, res);
  k_out     <<<1024, 256, 0, stream>>>(res, w4, gamma, beta, rmean, rvar, x, out);
}

// Round 4
// 191.693 us; speedup vs baseline: 1.0461x; 1.0461x over previous
//
#include <hip/hip_runtime.h>
#include <hip/hip_cooperative_groups.h>
#include <cstdint>

namespace cg = cooperative_groups;

#define BN 4
#define CIN 256
#define HALFC 128
#define HW 4096
#define SPLIT 4
#define JT 64
#define JITERS (HW / SPLIT / JT)   // 16

typedef float  floatx4 __attribute__((ext_vector_type(4)));
typedef short  shortx8 __attribute__((ext_vector_type(8)));

#if __has_builtin(__builtin_amdgcn_exp2f)
#define EXP2F(x) __builtin_amdgcn_exp2f(x)
#else
#define EXP2F(x) exp2f(x)
#endif
#define L2E 1.44269504088896f

__device__ __forceinline__ unsigned short f2bf(float f) {
  unsigned u = __float_as_uint(f);
  u += 0x7FFFu + ((u >> 16) & 1u);   // round-to-nearest-even
  return (unsigned short)(u >> 16);
}

__device__ __forceinline__ void async16(const void* g, void* l) {
  __builtin_amdgcn_global_load_lds((const __attribute__((address_space(1))) void*)g,
                                   (__attribute__((address_space(3))) void*)l, 16, 0, 0);
}

// ======================= phase bodies (shared: standalone + mega) =======================

// ---------------- P0: cast/transpose x -> Xt [b][px][ci] bf16; W -> Wh bf16 -----------
__device__ __forceinline__ void body_split(int vb, int t, float* smf,
    const float* __restrict__ x, const float* __restrict__ w1,
    const float* __restrict__ w2, const float* __restrict__ w3,
    unsigned short* __restrict__ Xth, unsigned short* __restrict__ Wh) {
  if (vb < 1024) {
    int b = vb >> 8, rem = vb & 255;
    int cit = rem >> 6, pxt = rem & 63;     // ci tile (4), px tile (64)
    const float* src = x + (size_t)b * 1048576 + (size_t)(cit * 64) * HW + pxt * 64;
#pragma unroll
    for (int k = 0; k < 16; k++) {
      int idx = k * 256 + t;
      int r = idx >> 6, c = idx & 63;
      smf[r * 65 + c] = src[(size_t)r * HW + c];
    }
    __syncthreads();
    int prow = t >> 2, seg = t & 3;
    union { unsigned short us[16]; uint4 v[2]; } oh;
#pragma unroll
    for (int u = 0; u < 16; u++)
      oh.us[u] = f2bf(smf[(seg * 16 + u) * 65 + prow]);
    size_t dst = (size_t)b * 1048576 + (size_t)(pxt * 64 + prow) * 256 + cit * 64 + seg * 16;
    *(uint4*)(Xth + dst) = oh.v[0];
    *(uint4*)(Xth + dst + 8) = oh.v[1];
  } else {
    int bw = vb - 1024;                     // 0..11, each block 8192 elems
    int f0 = bw * 8192 + t * 32;
    const float* wsrc;
    int fo;
    if (f0 < 32768)      { wsrc = w1; fo = f0; }
    else if (f0 < 65536) { wsrc = w2; fo = f0 - 32768; }
    else                 { wsrc = w3; fo = f0 - 65536; }
    union { unsigned short us[32]; uint4 v[4]; } oh;
#pragma unroll
    for (int u = 0; u < 32; u++) oh.us[u] = f2bf(wsrc[fo + u]);
#pragma unroll
    for (int k = 0; k < 4; k++) *((uint4*)(Wh + f0) + k) = oh.v[k];
  }
}

// ---------------- P1: MFMA projection (bf16, fp32 acc) ---------------------------------
__device__ __forceinline__ void body_projM(int vb, int t,
    unsigned short* XhS /*4096 shorts*/, unsigned short* ES /*9216 shorts*/,
    const unsigned short* __restrict__ Xth, const unsigned short* __restrict__ Wh,
    unsigned short* __restrict__ Q, unsigned short* __restrict__ Kt,
    unsigned short* __restrict__ n3) {
  int pxt = vb & 31;
  int ct = vb >> 5;                      // b*6 + cot
  int b = ct / 6, cot = ct % 6;
  int px0 = pxt * 128, co0 = cot * 64;
  int w = t >> 6, lane = t & 63, l16 = lane & 15, quad = lane >> 4;

  int myco = co0 + w * 16 + l16;
  shortx8 whf[8];
#pragma unroll
  for (int s = 0; s < 8; s++)
    whf[s] = *(const shortx8*)(Wh + (size_t)myco * 256 + s * 32 + quad * 8);
  floatx4 acc[8];
  floatx4 zf = {0.f, 0.f, 0.f, 0.f};
#pragma unroll
  for (int mt = 0; mt < 8; mt++) acc[mt] = zf;
  const unsigned short* XhB = Xth + (size_t)b * 1048576;
  int k8 = lane >> 4, pxm = lane & 15;

#pragma unroll
  for (int s = 0; s < 8; s++) {
    __syncthreads();
#pragma unroll
    for (int c2 = 0; c2 < 2; c2++) {     // stage fragment-order; lane L -> slot L*16
      int px = px0 + (c2 * 4 + w) * 16 + pxm;
      async16(XhB + (size_t)px * 256 + s * 32 + k8 * 8, (char*)XhS + c2 * 4096 + w * 1024);
    }
    __syncthreads();
#pragma unroll
    for (int mt = 0; mt < 8; mt++) {
      shortx8 ah = *(const shortx8*)((const char*)XhS + mt * 1024 + lane * 16);
      acc[mt] = __builtin_amdgcn_mfma_f32_16x16x32_bf16(ah, whf[s], acc[mt], 0, 0, 0);
    }
  }
  __syncthreads();
  // D layout: element [px = mt*16 + quad*4 + rr][co_l = w*16 + l16]
  if (cot < 2 || cot >= 4) {             // Q / n3: stage [co][px]
    int co_l = w * 16 + l16;
#pragma unroll
    for (int mt = 0; mt < 8; mt++) {
      int px = mt * 16 + quad * 4;
      unsigned lo = (unsigned)f2bf(acc[mt][0]) | ((unsigned)f2bf(acc[mt][1]) << 16);
      unsigned hi = (unsigned)f2bf(acc[mt][2]) | ((unsigned)f2bf(acc[mt][3]) << 16);
      *(uint2*)(ES + co_l * 136 + px) = make_uint2(lo, hi);
    }
    __syncthreads();
    int cr = t >> 2, seg = t & 3;
    unsigned short* dstb = (cot < 2)
        ? Q  + (size_t)b * 524288 + (size_t)(co0 + cr) * HW
        : n3 + (size_t)b * 524288 + (size_t)(co0 - 256 + cr) * HW;
#pragma unroll
    for (int k2 = 0; k2 < 4; k2++) {
      uint4 v = *(const uint4*)(ES + cr * 136 + seg * 32 + k2 * 8);
      *(uint4*)(dstb + px0 + seg * 32 + k2 * 8) = v;
    }
  } else {                               // Kt: stage [px][co]
#pragma unroll
    for (int mt = 0; mt < 8; mt++)
#pragma unroll
      for (int rr = 0; rr < 4; rr++) {
        int px = mt * 16 + quad * 4 + rr;
        ES[px * 72 + w * 16 + l16] = f2bf(acc[mt][rr]);
      }
    __syncthreads();
    int ch0 = co0 - 128;
#pragma unroll
    for (int it = 0; it < 4; it++) {
      int cid = it * 256 + t;
      int px = cid >> 3, c8 = cid & 7;
      uint4 v = *(const uint4*)(ES + px * 72 + c8 * 8);
      *(uint4*)(Kt + (size_t)b * 524288 + (size_t)(px0 + px) * 128 + ch0 + c8 * 8) = v;
    }
  }
}

// ---------------- P2: VtF: V in wave-fragment order for coalesced PV loads -------------
__device__ __forceinline__ void body_layoutVF(int vb, int t, unsigned short* sm,
    const unsigned short* __restrict__ n3, unsigned short* __restrict__ VtF) {
  int b = vb >> 6, jt = vb & 63;
  const unsigned short* src = n3 + (size_t)b * 524288 + (size_t)(jt * 2) * 4096;
#pragma unroll
  for (int k = 0; k < 32; k++) sm[k * 256 + t] = src[k * 256 + t];
  __syncthreads();
  unsigned short* dst = VtF + (size_t)b * 524288 + (size_t)jt * 8192;
#pragma unroll
  for (int k = 0; k < 4; k++) {
    int s = k * 256 + t;
    int nt = s >> 7, kt = (s >> 6) & 1, quad = (s >> 4) & 3, l16 = s & 15;
    union { unsigned short us[8]; uint4 v; } o;
#pragma unroll
    for (int e = 0; e < 8; e++)
      o.us[e] = sm[kt * 4096 + (quad * 8 + e) * 128 + nt * 16 + l16];
    *(uint4*)(dst + s * 8) = o.v;
  }
}

// ---------------- P3: fused flash attention (r2 structure, 61.3 us known-good) ---------
// T1 XCD swizzle + T13 defer-max + tree softmax + T5 setprio. 2 blocks/CU.
__device__ __forceinline__ void body_flash(int bid0, int t,
    unsigned short* KtS /*16384 shorts*/, unsigned short* PS /*8192 shorts*/,
    const unsigned short* __restrict__ Q, const unsigned short* __restrict__ Kt,
    const unsigned short* __restrict__ VtF, float* __restrict__ Opart,
    float* __restrict__ ml) {
  int bid = (bid0 & 7) * 64 + (bid0 >> 3);   // T1: 512 blocks -> 64-block chunk per XCD
  int itile = bid & 31, sp = (bid >> 5) & 3, b = bid >> 7;
  int w = t >> 6, lane = t & 63, l16 = lane & 15, quad = lane >> 4;
  int i0 = itile * 128;

  shortx8 qf[2][4];
#pragma unroll
  for (int ig = 0; ig < 2; ig++) {
    const unsigned short* qp = Q + ((size_t)b * HW + i0 + w * 32 + ig * 16 + l16) * 128 + quad * 8;
#pragma unroll
    for (int ks = 0; ks < 4; ks++) qf[ig][ks] = *(const shortx8*)(qp + ks * 32);
  }
  __asm__ __volatile__("s_waitcnt vmcnt(0)" ::: "memory");  // drain Q loads

  floatx4 O[2][8];
  floatx4 zf = {0.f, 0.f, 0.f, 0.f};
#pragma unroll
  for (int ig = 0; ig < 2; ig++)
#pragma unroll
    for (int nt = 0; nt < 8; nt++) O[ig][nt] = zf;
  float m_i[2] = {-1e30f, -1e30f}, l_i[2] = {0.f, 0.f};

  int ccK = w * 4 + quad;
  const unsigned short* kbase = Kt + (size_t)b * HW * 128
                              + (size_t)(sp * 1024 + l16) * 128 + ccK * 8;
  const unsigned short* vB = VtF + (size_t)b * 524288 + (size_t)(sp * 16) * 8192 + lane * 8;
  char* Pw = (char*)PS + w * 4096;

  // prologue: stage Kt tile 0 into buffer 0 (4 async16, left in flight)
#pragma unroll
  for (int c4 = 0; c4 < 4; c4++)
    async16(kbase + c4 * 2048, (char*)KtS + c4 * 4096 + w * 1024);

  for (int it = 0; it < JITERS; it++) {
    int cur = it & 1, nxt = cur ^ 1;
    // barrier A: compute(it-1) done -> KtS[nxt] free
    __asm__ __volatile__("s_barrier" ::: "memory");
    // vf loads for tile it (global, coalesced) — ISSUED BEFORE prefetch (vmcnt order!)
    shortx8 vf[8][2];
    {
      const unsigned short* vt = vB + (size_t)it * 8192;
#pragma unroll
      for (int nt = 0; nt < 8; nt++)
#pragma unroll
        for (int kt = 0; kt < 2; kt++)
          vf[nt][kt] = *(const shortx8*)(vt + (nt * 2 + kt) * 512);
    }
    if (it + 1 < JITERS) {
      const unsigned short* kp = kbase + (size_t)(it + 1) * 8192;
#pragma unroll
      for (int c4 = 0; c4 < 4; c4++)
        async16(kp + c4 * 2048, (char*)KtS + nxt * 8192 * 2 + c4 * 4096 + w * 1024);
      // drain tile-it staging only (leaves 16 vf + 4 prefetch in flight)
      __asm__ __volatile__("s_waitcnt vmcnt(20)" ::: "memory");
    } else {
      __asm__ __volatile__("s_waitcnt vmcnt(16)" ::: "memory");
    }
    // barrier B: all waves' tile-it Kt loads landed
    __asm__ __volatile__("s_barrier" ::: "memory");

    const char* kc = (const char*)KtS + cur * 16384;

    // ---- QK: S^T[j][i]; each af feeds both i-groups ----
    floatx4 S[2][4];
#pragma unroll
    for (int ig = 0; ig < 2; ig++)
#pragma unroll
      for (int mt = 0; mt < 4; mt++) S[ig][mt] = zf;
    __builtin_amdgcn_s_setprio(1);
#pragma unroll
    for (int mt = 0; mt < 4; mt++) {
#pragma unroll
      for (int ks = 0; ks < 4; ks++) {
        shortx8 af = *(const shortx8*)(kc + mt * 4096 + ks * 1024 + lane * 16);
        S[0][mt] = __builtin_amdgcn_mfma_f32_16x16x32_bf16(af, qf[0][ks], S[0][mt], 0, 0, 0);
        S[1][mt] = __builtin_amdgcn_mfma_f32_16x16x32_bf16(af, qf[1][ks], S[1][mt], 0, 0, 0);
      }
    }
    __builtin_amdgcn_s_setprio(0);

    // ---- max phase (tree, depth 4) ----
    float tmax[2];
#pragma unroll
    for (int ig = 0; ig < 2; ig++) {
      float a0 = fmaxf(fmaxf(S[ig][0][0], S[ig][0][1]), fmaxf(S[ig][0][2], S[ig][0][3]));
      float a1 = fmaxf(fmaxf(S[ig][1][0], S[ig][1][1]), fmaxf(S[ig][1][2], S[ig][1][3]));
      float a2 = fmaxf(fmaxf(S[ig][2][0], S[ig][2][1]), fmaxf(S[ig][2][2], S[ig][2][3]));
      float a3 = fmaxf(fmaxf(S[ig][3][0], S[ig][3][1]), fmaxf(S[ig][3][2], S[ig][3][3]));
      float tm = fmaxf(fmaxf(a0, a1), fmaxf(a2, a3));
      tm = fmaxf(tm, __shfl_xor(tm, 16));
      tm = fmaxf(tm, __shfl_xor(tm, 32));
      tmax[ig] = tm;
    }
    // ---- T13 defer-max: only touch m/O when some row grew by > 8 nats ----
    float alpha[2] = {1.f, 1.f};
    if (__ballot(tmax[0] > m_i[0] + 8.f || tmax[1] > m_i[1] + 8.f)) {
#pragma unroll
      for (int ig = 0; ig < 2; ig++) {
        float mn = fmaxf(m_i[ig], tmax[ig]);
        alpha[ig] = EXP2F((m_i[ig] - mn) * L2E);
        m_i[ig] = mn;
        float ar[4];
#pragma unroll
        for (int rr = 0; rr < 4; rr++) ar[rr] = __shfl(alpha[ig], quad * 4 + rr);
#pragma unroll
        for (int nt = 0; nt < 8; nt++)
#pragma unroll
          for (int rr = 0; rr < 4; rr++) O[ig][nt][rr] *= ar[rr];
      }
    }
    // ---- exp / sum (tree) / pack; P overwrites S ----
#pragma unroll
    for (int ig = 0; ig < 2; ig++) {
      float nsc = m_i[ig] * L2E;
      float sm[4];
#pragma unroll
      for (int mt = 0; mt < 4; mt++) {
        float p0 = EXP2F(fmaf(S[ig][mt][0], L2E, -nsc));
        float p1 = EXP2F(fmaf(S[ig][mt][1], L2E, -nsc));
        float p2 = EXP2F(fmaf(S[ig][mt][2], L2E, -nsc));
        float p3 = EXP2F(fmaf(S[ig][mt][3], L2E, -nsc));
        S[ig][mt][0] = p0; S[ig][mt][1] = p1; S[ig][mt][2] = p2; S[ig][mt][3] = p3;
        sm[mt] = (p0 + p1) + (p2 + p3);
      }
      float ts = (sm[0] + sm[1]) + (sm[2] + sm[3]);
      ts += __shfl_xor(ts, 16);
      ts += __shfl_xor(ts, 32);
      l_i[ig] = l_i[ig] * alpha[ig] + ts;
      // truncating bf16 pack via v_perm (1 inst/pair)
#pragma unroll
      for (int mt = 0; mt < 4; mt++) {
        unsigned lo = __builtin_amdgcn_perm(__float_as_uint(S[ig][mt][1]),
                                            __float_as_uint(S[ig][mt][0]), 0x07060302u);
        unsigned hi = __builtin_amdgcn_perm(__float_as_uint(S[ig][mt][3]),
                                            __float_as_uint(S[ig][mt][2]), 0x07060302u);
        *(uint2*)(Pw + ig * 2048 + (mt * 2 + (quad >> 1)) * 256 + l16 * 16 + (quad & 1) * 8)
            = make_uint2(lo, hi);
      }
    }
    __asm__ __volatile__("s_waitcnt lgkmcnt(0)" ::: "memory");  // PS write->read
    // vf arrival (vf older than prefetch: vmcnt(4) leaves prefetch in flight)
    if (it + 1 < JITERS) {
      __asm__ __volatile__("s_waitcnt vmcnt(4)" ::: "memory");
    } else {
      __asm__ __volatile__("s_waitcnt vmcnt(0)" ::: "memory");
    }
    // ---- PV from registers ----
    __builtin_amdgcn_s_setprio(1);
#pragma unroll
    for (int kt = 0; kt < 2; kt++) {
      shortx8 pf0 = *(const shortx8*)(Pw + kt * 1024 + lane * 16);
      shortx8 pf1 = *(const shortx8*)(Pw + 2048 + kt * 1024 + lane * 16);
#pragma unroll
      for (int nt = 0; nt < 8; nt++) {
        O[0][nt] = __builtin_amdgcn_mfma_f32_16x16x32_bf16(pf0, vf[nt][kt], O[0][nt], 0, 0, 0);
        O[1][nt] = __builtin_amdgcn_mfma_f32_16x16x32_bf16(pf1, vf[nt][kt], O[1][nt], 0, 0, 0);
      }
    }
    __builtin_amdgcn_s_setprio(0);
  }
  // epilogue: store partial O and (m,l)
#pragma unroll
  for (int ig = 0; ig < 2; ig++) {
    float* Ob = Opart + ((size_t)(sp * 4 + b) * HW + i0 + w * 32 + ig * 16) * 128;
#pragma unroll
    for (int nt = 0; nt < 8; nt++)
#pragma unroll
      for (int rr = 0; rr < 4; rr++)
        Ob[(size_t)(quad * 4 + rr) * 128 + nt * 16 + l16] = O[ig][nt][rr];
  }
  if (quad == 0) {
    float2* mlp = (float2*)ml;
#pragma unroll
    for (int ig = 0; ig < 2; ig++)
      mlp[(size_t)(sp * 4 + b) * HW + i0 + w * 32 + ig * 16 + l16]
          = make_float2(m_i[ig], l_i[ig]);
  }
}

// ---------------- P4: merge split-j partials -> res ------------------------------------
__device__ __forceinline__ void body_merge(int vb, int t,
    const float* __restrict__ Opart, const float* __restrict__ ml,
    float* __restrict__ res) {
  size_t e = (size_t)vb * 256 + t;       // float4 index
  int cq = (int)(e & 31);
  int i = (int)((e >> 5) & 4095);
  int b = (int)(e >> 17);
  const float2* mlp = (const float2*)ml;
  float m[SPLIT], l[SPLIT];
  float M = -1e30f;
#pragma unroll
  for (int s = 0; s < SPLIT; s++) {
    float2 st = mlp[(size_t)(s * 4 + b) * HW + i];
    m[s] = st.x; l[s] = st.y;
    M = fmaxf(M, m[s]);
  }
  float denom = 0.f;
  float wgt[SPLIT];
#pragma unroll
  for (int s = 0; s < SPLIT; s++) {
    float ws_ = EXP2F((m[s] - M) * L2E);
    wgt[s] = ws_;
    denom += l[s] * ws_;
  }
  float inv = 1.f / denom;
  floatx4 acc = {0.f, 0.f, 0.f, 0.f};
#pragma unroll
  for (int s = 0; s < SPLIT; s++) {
    floatx4 v = *(const floatx4*)(Opart + ((size_t)(s * 4 + b) * HW + i) * 128 + cq * 4);
    acc += v * (wgt[s] * inv);
  }
  *(floatx4*)(res + e * 4) = acc;
}

// ---------------- P5: conv4 (fp32) + BN(eval) + residual ------------------------------
__device__ __forceinline__ void body_out(int vb, int t, float* wt /*16*128 f32*/,
    const float* __restrict__ res, const float* __restrict__ w4,
    const float* __restrict__ gamma, const float* __restrict__ beta,
    const float* __restrict__ rmean, const float* __restrict__ rvar,
    const float* __restrict__ x, float* __restrict__ out) {
  int cot = vb & 15;
  int st = (vb >> 4) & 15;
  int b = vb >> 8;
  int co0 = cot * 16;
#pragma unroll
  for (int k = 0; k < 8; k++) wt[k * 256 + t] = w4[(size_t)co0 * 128 + k * 256 + t];
  __syncthreads();
  int px = st * 256 + t;
  const float* rb = res + (size_t)b * 524288 + px;
  float acc[16];
#pragma unroll
  for (int r = 0; r < 16; r++) acc[r] = 0.f;
  for (int ci = 0; ci < 128; ci += 4) {
    float xv[4];
#pragma unroll
    for (int kk = 0; kk < 4; kk++) xv[kk] = rb[(size_t)(ci + kk) * HW];
#pragma unroll
    for (int r = 0; r < 16; r++) {
      floatx4 wv = *(const floatx4*)&wt[r * 128 + ci];
#pragma unroll
      for (int kk = 0; kk < 4; kk++) acc[r] += wv[kk] * xv[kk];
    }
  }
  const float* xb = x + ((size_t)b * 256 + co0) * HW + px;
  float* ob = out + ((size_t)b * 256 + co0) * HW + px;
#pragma unroll
  for (int r = 0; r < 16; r++) {
    int co = co0 + r;
    float g = gamma[co] * rsqrtf(rvar[co] + 1e-5f);
    float bb = beta[co] - rmean[co] * g;
    ob[(size_t)r * HW] = acc[r] * g + bb + xb[(size_t)r * HW];
  }
}

// ======================= standalone kernels (fallback path) =============================

__global__ __launch_bounds__(256) void k_split(const float* __restrict__ x,
    const float* __restrict__ w1, const float* __restrict__ w2,
    const float* __restrict__ w3, unsigned short* __restrict__ Xth,
    unsigned short* __restrict__ Wh) {
  __shared__ float smf[64 * 65];
  body_split(blockIdx.x, threadIdx.x, smf, x, w1, w2, w3, Xth, Wh);
}

__global__ __launch_bounds__(256) void k_projM(const unsigned short* __restrict__ Xth,
    const unsigned short* __restrict__ Wh, unsigned short* __restrict__ Q,
    unsigned short* __restrict__ Kt, unsigned short* __restrict__ n3) {
  __shared__ unsigned short XhS[4096];
  __shared__ unsigned short ES[9216];
  body_projM(blockIdx.x, threadIdx.x, XhS, ES, Xth, Wh, Q, Kt, n3);
}

__global__ __launch_bounds__(256) void k_layoutVF(const unsigned short* __restrict__ n3,
    unsigned short* __restrict__ VtF) {
  __shared__ unsigned short sm[8192];
  body_layoutVF(blockIdx.x, threadIdx.x, sm, n3, VtF);
}

__global__ __launch_bounds__(256, 2) void k_flash(const unsigned short* __restrict__ Q,
    const unsigned short* __restrict__ Kt, const unsigned short* __restrict__ VtF,
    float* __restrict__ Opart, float* __restrict__ ml) {
  __shared__ unsigned short KtS[2 * 8192];
  __shared__ unsigned short PS[4 * 32 * 64];
  body_flash(blockIdx.x, threadIdx.x, KtS, PS, Q, Kt, VtF, Opart, ml);
}

__global__ __launch_bounds__(256) void k_merge(const float* __restrict__ Opart,
    const float* __restrict__ ml, float* __restrict__ res) {
  body_merge(blockIdx.x, threadIdx.x, Opart, ml, res);
}

__global__ __launch_bounds__(256) void k_out(const float* __restrict__ res,
    const float* __restrict__ w4, const float* __restrict__ gamma,
    const float* __restrict__ beta, const float* __restrict__ rmean,
    const float* __restrict__ rvar, const float* __restrict__ x,
    float* __restrict__ out) {
  __shared__ float wt[16 * 128];
  body_out(blockIdx.x, threadIdx.x, wt, res, w4, gamma, beta, rmean, rvar, x, out);
}

// ======================= cooperative mega-kernel ========================================
// 512 blocks x 256 threads (2 blocks/CU: LDS 48KB, VGPR<=128-ish). All 6 phases with
// grid.sync() between; per-phase native grids re-mapped by grid-stride. Eliminates 5
// kernel-launch overheads and doubles k_layoutVF's TLP. Phase bodies are the exact r2
// code (shared __device__ functions) -> bit-identical math.
__global__ __launch_bounds__(256, 2) void k_mega(
    const float* __restrict__ x, const float* __restrict__ w1,
    const float* __restrict__ w2, const float* __restrict__ w3,
    const float* __restrict__ w4, const float* __restrict__ gamma,
    const float* __restrict__ beta, const float* __restrict__ rmean,
    const float* __restrict__ rvar, float* __restrict__ out,
    unsigned short* __restrict__ Xth, unsigned short* __restrict__ Wh,
    unsigned short* __restrict__ Q, unsigned short* __restrict__ Kt,
    unsigned short* __restrict__ n3, unsigned short* __restrict__ VtF,
    float* __restrict__ Opart, float* __restrict__ ml, float* __restrict__ res) {
  cg::grid_group grid = cg::this_grid();
  __shared__ __align__(16) char smem[49152];   // max over phases (flash: 32K + 16K)
  int t = threadIdx.x;
  int bid = blockIdx.x;

  // P0: split (1036 vblocks)
  for (int vb = bid; vb < 1036; vb += 512) {
    __syncthreads();                     // WAR on smem between vb iterations
    body_split(vb, t, (float*)smem, x, w1, w2, w3, Xth, Wh);
  }
  grid.sync();

  // P1: projection (768 vblocks)
  for (int vb = bid; vb < 768; vb += 512) {
    __syncthreads();
    body_projM(vb, t, (unsigned short*)smem, (unsigned short*)(smem + 8192),
               Xth, Wh, Q, Kt, n3);
  }
  grid.sync();

  // P2: V fragment layout (256 vblocks)
  for (int vb = bid; vb < 256; vb += 512) {
    __syncthreads();
    body_layoutVF(vb, t, (unsigned short*)smem, n3, VtF);
  }
  grid.sync();

  // P3: flash attention (512 vblocks, 1:1)
  __syncthreads();
  body_flash(bid, t, (unsigned short*)smem, (unsigned short*)(smem + 32768),
             Q, Kt, VtF, Opart, ml);
  grid.sync();

  // P4: merge (2048 vblocks)
  for (int vb = bid; vb < 2048; vb += 512)
    body_merge(vb, t, Opart, ml, res);
  grid.sync();

  // P5: conv4 + BN + residual (1024 vblocks)
  for (int vb = bid; vb < 1024; vb += 512) {
    __syncthreads();
    body_out(vb, t, (float*)smem, res, w4, gamma, beta, rmean, rvar, x, out);
  }
}

extern "C" void kernel_launch(void* const* d_in, const int* in_sizes, int n_in,
                              void* d_out, int out_size, void* d_ws, size_t ws_size,
                              hipStream_t stream) {
  const float* x     = (const float*)d_in[0];
  const float* w1    = (const float*)d_in[1];
  const float* w2    = (const float*)d_in[2];
  const float* w3    = (const float*)d_in[3];
  const float* w4    = (const float*)d_in[4];
  const float* gamma = (const float*)d_in[5];
  const float* beta  = (const float*)d_in[6];
  const float* rmean = (const float*)d_in[7];
  const float* rvar  = (const float*)d_in[8];
  float* out = (float*)d_out;
  char* ws = (char*)d_ws;

  // Opart region (32 MB) overlaps n3 / Xth (dead before flash phase runs)
  size_t off = (size_t)SPLIT * 4 * HW * 128 * 4;             // 32 MB
  float* Opart = (float*)ws;
  unsigned short* n3  = (unsigned short*)ws;                  // 4.2 MB @ 0
  unsigned short* Xth = (unsigned short*)(ws + ((size_t)8 << 20));   // 8.4 MB @ 8M
  unsigned short* Q   = (unsigned short*)(ws + off); off += (size_t)4 * HW * 128 * 2;
  unsigned short* Kt  = (unsigned short*)(ws + off); off += (size_t)4 * HW * 128 * 2;
  unsigned short* VtF = (unsigned short*)(ws + off); off += (size_t)4 * HW * 128 * 2;
  float* ml  = (float*)(ws + off); off += (size_t)SPLIT * 4 * HW * 2 * 4;
  float* res = (float*)(ws + off); off += (size_t)4 * HW * 128 * 4;
  unsigned short* Wh = (unsigned short*)(ws + off); off += (size_t)384 * 256 * 2;
  if (ws_size < off) return;

  // Cooperative path: decided once by occupancy (needs 2 blocks/CU x 256 CUs >= 512).
  static int coop = -1;
  if (coop < 0) {
    int nb = 0;
    hipError_t e = hipOccupancyMaxActiveBlocksPerMultiprocessor(
        &nb, (const void*)k_mega, 256, 0);
    coop = (e == hipSuccess && nb >= 2) ? 1 : 0;
  }
  if (coop == 1) {
    void* args[] = {(void*)&x, (void*)&w1, (void*)&w2, (void*)&w3, (void*)&w4,
                    (void*)&gamma, (void*)&beta, (void*)&rmean, (void*)&rvar,
                    (void*)&out, (void*)&Xth, (void*)&Wh, (void*)&Q, (void*)&Kt,
                    (void*)&n3, (void*)&VtF, (void*)&Opart, (void*)&ml, (void*)&res};
    hipError_t e = hipLaunchCooperativeKernel((const void*)k_mega, dim3(512),
                                              dim3(256), args, 0, stream);
    if (e == hipSuccess) return;
    coop = 0;  // fall through to classic path
  }

  k_split   <<<1036, 256, 0, stream>>>(x, w1, w2, w3, Xth, Wh);
  k_projM   <<<768,  256, 0, stream>>>(Xth, Wh, Q, Kt, n3);
  k_layoutVF<<<256,  256, 0, stream>>>(n3, VtF);
  k_flash   <<<512,  256, 0, stream>>>(Q, Kt, VtF, Opart, ml);
  k_merge   <<<2048, 256, 0, stream>>>(Opart, ml, res);
  k_out     <<<1024, 256, 0, stream>>>(res, w4, gamma, beta, rmean, rvar, x, out);
}

// Round 5
// 186.532 us; speedup vs baseline: 1.0750x; 1.0277x over previous
//
#include <hip/hip_runtime.h>
#include <cstdint>

#define BN 4
#define CIN 256
#define HALFC 128
#define HW 4096
#define SPLIT 4
#define JT 64
#define JITERS (HW / SPLIT / JT)   // 16

typedef float  floatx4 __attribute__((ext_vector_type(4)));
typedef short  shortx8 __attribute__((ext_vector_type(8)));

#if __has_builtin(__builtin_amdgcn_exp2f)
#define EXP2F(x) __builtin_amdgcn_exp2f(x)
#else
#define EXP2F(x) exp2f(x)
#endif
#define L2E 1.44269504088896f

__device__ __forceinline__ unsigned short f2bf(float f) {
  unsigned u = __float_as_uint(f);
  u += 0x7FFFu + ((u >> 16) & 1u);   // round-to-nearest-even
  return (unsigned short)(u >> 16);
}

__device__ __forceinline__ void async16(const void* g, void* l) {
  __builtin_amdgcn_global_load_lds((const __attribute__((address_space(1))) void*)g,
                                   (__attribute__((address_space(3))) void*)l, 16, 0, 0);
}

// ---------------- K0: cast/transpose x -> Xt [b][px][ci] bf16; W -> Wh bf16 -----------
__global__ __launch_bounds__(256) void k_split(const float* __restrict__ x,
    const float* __restrict__ w1, const float* __restrict__ w2,
    const float* __restrict__ w3, unsigned short* __restrict__ Xth,
    unsigned short* __restrict__ Wh) {
  __shared__ float smf[64 * 65];
  int bid = blockIdx.x;
  int t = threadIdx.x;
  if (bid < 1024) {
    int b = bid >> 8, rem = bid & 255;
    int cit = rem >> 6, pxt = rem & 63;     // ci tile (4), px tile (64)
    const float* src = x + (size_t)b * 1048576 + (size_t)(cit * 64) * HW + pxt * 64;
#pragma unroll
    for (int k = 0; k < 16; k++) {
      int idx = k * 256 + t;
      int r = idx >> 6, c = idx & 63;
      smf[r * 65 + c] = src[(size_t)r * HW + c];
    }
    __syncthreads();
    int prow = t >> 2, seg = t & 3;
    union { unsigned short us[16]; uint4 v[2]; } oh;
#pragma unroll
    for (int u = 0; u < 16; u++)
      oh.us[u] = f2bf(smf[(seg * 16 + u) * 65 + prow]);
    size_t dst = (size_t)b * 1048576 + (size_t)(pxt * 64 + prow) * 256 + cit * 64 + seg * 16;
    *(uint4*)(Xth + dst) = oh.v[0];
    *(uint4*)(Xth + dst + 8) = oh.v[1];
  } else {
    int bw = bid - 1024;                    // 0..11, each block 8192 elems
    int f0 = bw * 8192 + t * 32;
    const float* wsrc;
    int fo;
    if (f0 < 32768)      { wsrc = w1; fo = f0; }
    else if (f0 < 65536) { wsrc = w2; fo = f0 - 32768; }
    else                 { wsrc = w3; fo = f0 - 65536; }
    union { unsigned short us[32]; uint4 v[4]; } oh;
#pragma unroll
    for (int u = 0; u < 32; u++) oh.us[u] = f2bf(wsrc[fo + u]);
#pragma unroll
    for (int k = 0; k < 4; k++) *((uint4*)(Wh + f0) + k) = oh.v[k];
  }
}

// ---------------- K1: MFMA projection (bf16, fp32 acc) ---------------------------------
__global__ __launch_bounds__(256) void k_projM(const unsigned short* __restrict__ Xth,
    const unsigned short* __restrict__ Wh, unsigned short* __restrict__ Q,
    unsigned short* __restrict__ Kt, unsigned short* __restrict__ n3) {
  __shared__ unsigned short XhS[4096];   // [128 px][32 ci] fragment order, 8 KB
  __shared__ unsigned short ES[9216];    // epilogue stage
  int bid = blockIdx.x;
  int pxt = bid & 31;
  int ct = bid >> 5;                     // b*6 + cot
  int b = ct / 6, cot = ct % 6;
  int px0 = pxt * 128, co0 = cot * 64;
  int t = threadIdx.x;
  int w = t >> 6, lane = t & 63, l16 = lane & 15, quad = lane >> 4;

  int myco = co0 + w * 16 + l16;
  shortx8 whf[8];
#pragma unroll
  for (int s = 0; s < 8; s++)
    whf[s] = *(const shortx8*)(Wh + (size_t)myco * 256 + s * 32 + quad * 8);
  floatx4 acc[8];
  floatx4 zf = {0.f, 0.f, 0.f, 0.f};
#pragma unroll
  for (int mt = 0; mt < 8; mt++) acc[mt] = zf;
  const unsigned short* XhB = Xth + (size_t)b * 1048576;
  int k8 = lane >> 4, pxm = lane & 15;

#pragma unroll
  for (int s = 0; s < 8; s++) {
    __syncthreads();
#pragma unroll
    for (int c2 = 0; c2 < 2; c2++) {     // stage fragment-order; lane L -> slot L*16
      int px = px0 + (c2 * 4 + w) * 16 + pxm;
      async16(XhB + (size_t)px * 256 + s * 32 + k8 * 8, (char*)XhS + c2 * 4096 + w * 1024);
    }
    __syncthreads();
#pragma unroll
    for (int mt = 0; mt < 8; mt++) {
      shortx8 ah = *(const shortx8*)((const char*)XhS + mt * 1024 + lane * 16);
      acc[mt] = __builtin_amdgcn_mfma_f32_16x16x32_bf16(ah, whf[s], acc[mt], 0, 0, 0);
    }
  }
  __syncthreads();
  // D layout: element [px = mt*16 + quad*4 + rr][co_l = w*16 + l16]
  if (cot < 2 || cot >= 4) {             // Q / n3: stage [co][px]
    int co_l = w * 16 + l16;
#pragma unroll
    for (int mt = 0; mt < 8; mt++) {
      int px = mt * 16 + quad * 4;
      unsigned lo = (unsigned)f2bf(acc[mt][0]) | ((unsigned)f2bf(acc[mt][1]) << 16);
      unsigned hi = (unsigned)f2bf(acc[mt][2]) | ((unsigned)f2bf(acc[mt][3]) << 16);
      *(uint2*)(ES + co_l * 136 + px) = make_uint2(lo, hi);
    }
    __syncthreads();
    int cr = t >> 2, seg = t & 3;
    unsigned short* dstb = (cot < 2)
        ? Q  + (size_t)b * 524288 + (size_t)(co0 + cr) * HW
        : n3 + (size_t)b * 524288 + (size_t)(co0 - 256 + cr) * HW;
#pragma unroll
    for (int k2 = 0; k2 < 4; k2++) {
      uint4 v = *(const uint4*)(ES + cr * 136 + seg * 32 + k2 * 8);
      *(uint4*)(dstb + px0 + seg * 32 + k2 * 8) = v;
    }
  } else {                               // Kt: stage [px][co]
#pragma unroll
    for (int mt = 0; mt < 8; mt++)
#pragma unroll
      for (int rr = 0; rr < 4; rr++) {
        int px = mt * 16 + quad * 4 + rr;
        ES[px * 72 + w * 16 + l16] = f2bf(acc[mt][rr]);
      }
    __syncthreads();
    int ch0 = co0 - 128;
#pragma unroll
    for (int it = 0; it < 4; it++) {
      int cid = it * 256 + t;
      int px = cid >> 3, c8 = cid & 7;
      uint4 v = *(const uint4*)(ES + px * 72 + c8 * 8);
      *(uint4*)(Kt + (size_t)b * 524288 + (size_t)(px0 + px) * 128 + ch0 + c8 * 8) = v;
    }
  }
}

// ---------------- K2: VtF: V in wave-fragment order for direct coalesced PV loads ------
// slot s = (nt*2+kt)*64 + quad*16 + l16 holds V[j = jt*64+kt*32+quad*8+e][c = nt*16+l16]
__global__ __launch_bounds__(256) void k_layoutVF(const unsigned short* __restrict__ n3,
    unsigned short* __restrict__ VtF) {
  __shared__ unsigned short sm[8192];
  int bid = blockIdx.x;                  // 256 = b(4) x jt(64)
  int b = bid >> 6, jt = bid & 63;
  int t = threadIdx.x;
  const unsigned short* src = n3 + (size_t)b * 524288 + (size_t)(jt * 2) * 4096;
#pragma unroll
  for (int k = 0; k < 32; k++) sm[k * 256 + t] = src[k * 256 + t];
  __syncthreads();
  unsigned short* dst = VtF + (size_t)b * 524288 + (size_t)jt * 8192;
#pragma unroll
  for (int k = 0; k < 4; k++) {
    int s = k * 256 + t;
    int nt = s >> 7, kt = (s >> 6) & 1, quad = (s >> 4) & 3, l16 = s & 15;
    union { unsigned short us[8]; uint4 v; } o;
#pragma unroll
    for (int e = 0; e < 8; e++)
      o.us[e] = sm[kt * 4096 + (quad * 8 + e) * 128 + nt * 16 + l16];
    *(uint4*)(dst + s * 8) = o.v;
  }
}

// ---------------- K3: fused flash attention (deferred-PV, V via LDS) --------------------
// r3's T15 deferred-PV failed on registers (vf dbuf +64 VGPR -> spill). This version
// keeps the pipeline but moves V to LDS: VS dbuf staged via global_load_lds one iter
// ahead. LDS = KtS dbuf 32K + VS dbuf 32K + PS 16K = 80K = exactly 2 blocks/CU.
// PS single-buffer is safe: wave-private + per-wave in-order DS => PV(t-1) reads precede
// pack(t) writes. Per iter: one 64-MFMA cluster (PV(t-1)+QK(t)), softmax overlaps the
// next staging window; no per-iter vmcnt stall on V. Math telescopes as r2:
// O = (O + P(t-1)V(t-1)) * alpha(t); epilogue adds P(15)V(15).
// Buffer lifetimes: K(u) in KtS[u&1] staged at top of iter u-1; V(u) in VS[u&1] staged
// AFTER cluster(u-1) (barC guarantees PV(u-2)'s reads of VS[u&1] are done).
__global__ __launch_bounds__(256, 2) void k_flash(const unsigned short* __restrict__ Q,
    const unsigned short* __restrict__ Kt, const unsigned short* __restrict__ VtF,
    float* __restrict__ Opart, float* __restrict__ ml) {
  __shared__ unsigned short KtS[2 * 8192];   // 32 KB dbuf
  __shared__ unsigned short VS[2 * 8192];    // 32 KB dbuf
  __shared__ unsigned short PS[4 * 2048];    // 16 KB (4 KB per wave, single)
  int bid0 = blockIdx.x;
  int bid = (bid0 & 7) * 64 + (bid0 >> 3);   // T1: 512 blocks -> 64-block chunk per XCD
  int itile = bid & 31, sp = (bid >> 5) & 3, b = bid >> 7;
  int t = threadIdx.x;
  int w = t >> 6, lane = t & 63, l16 = lane & 15, quad = lane >> 4;
  int i0 = itile * 128;

  shortx8 qf[2][4];
#pragma unroll
  for (int ig = 0; ig < 2; ig++) {
    const unsigned short* qp = Q + ((size_t)b * HW + i0 + w * 32 + ig * 16 + l16) * 128 + quad * 8;
#pragma unroll
    for (int ks = 0; ks < 4; ks++) qf[ig][ks] = *(const shortx8*)(qp + ks * 32);
  }
  __asm__ __volatile__("s_waitcnt vmcnt(0)" ::: "memory");  // drain Q loads

  floatx4 O[2][8];
  floatx4 zf = {0.f, 0.f, 0.f, 0.f};
#pragma unroll
  for (int ig = 0; ig < 2; ig++)
#pragma unroll
    for (int nt = 0; nt < 8; nt++) O[ig][nt] = zf;
  float m_i[2] = {-1e30f, -1e30f}, l_i[2] = {0.f, 0.f};

  int ccK = w * 4 + quad;
  const unsigned short* kbase = Kt + (size_t)b * HW * 128
                              + (size_t)(sp * 1024 + l16) * 128 + ccK * 8;
  // per-lane V source: linear VtF tile; lane L supplies shorts [c4*2048 + w*512 + L*8 ..+8)
  const unsigned short* vbase = VtF + (size_t)b * 524288 + (size_t)(sp * 16) * 8192
                              + w * 512 + lane * 8;
  char* Pw = (char*)PS + w * 4096;

  // prologue: stage K(0) -> KtS[0], V(0) -> VS[0] (8 async16/wave, left in flight)
#pragma unroll
  for (int c4 = 0; c4 < 4; c4++) {
    async16(kbase + c4 * 2048, (char*)KtS + c4 * 4096 + w * 1024);
    async16(vbase + c4 * 2048, (char*)VS + c4 * 4096 + w * 1024);
  }

  for (int it = 0; it < JITERS; it++) {
    int cur = it & 1, nxt = cur ^ 1;
    // stage K(it+1) into KtS[nxt]; prev barC guarantees QK(it-1)'s reads of it are done
    if (it + 1 < JITERS) {
      const unsigned short* kp = kbase + (size_t)(it + 1) * 8192;
#pragma unroll
      for (int c4 = 0; c4 < 4; c4++)
        async16(kp + c4 * 2048, (char*)KtS + nxt * 16384 + c4 * 4096 + w * 1024);
      // queue: [K(it)(4), V(it)(4), K(it+1)(4)] -> drain K(it)+V(it), keep K(it+1)
      __asm__ __volatile__("s_waitcnt vmcnt(4)" ::: "memory");
    } else {
      __asm__ __volatile__("s_waitcnt vmcnt(0)" ::: "memory");
    }
    // barB: all waves' K(it)/V(it) staging visible
    __asm__ __volatile__("s_barrier" ::: "memory");
    __asm__ __volatile__("s_waitcnt lgkmcnt(0)" ::: "memory");  // stale pack writes (free)

    const char* kc = (const char*)KtS + cur * 16384;
    const char* vc = (const char*)VS + cur * 16384;

    // ---- MFMA cluster: PV(it-1) + QK(it), back-to-back, no waits inside ----
    floatx4 S[2][4];
#pragma unroll
    for (int ig = 0; ig < 2; ig++)
#pragma unroll
      for (int mt = 0; mt < 4; mt++) S[ig][mt] = zf;
    __builtin_amdgcn_s_setprio(1);
    if (it > 0) {
      const char* vp = (const char*)VS + nxt * 16384;   // V(it-1) lives in VS[(it-1)&1]
#pragma unroll
      for (int kt = 0; kt < 2; kt++) {
        shortx8 pf0 = *(const shortx8*)(Pw + kt * 1024 + lane * 16);
        shortx8 pf1 = *(const shortx8*)(Pw + 2048 + kt * 1024 + lane * 16);
#pragma unroll
        for (int nt = 0; nt < 8; nt++) {
          shortx8 vfr = *(const shortx8*)(vp + ((nt * 2 + kt) * 64 + lane) * 16);
          O[0][nt] = __builtin_amdgcn_mfma_f32_16x16x32_bf16(pf0, vfr, O[0][nt], 0, 0, 0);
          O[1][nt] = __builtin_amdgcn_mfma_f32_16x16x32_bf16(pf1, vfr, O[1][nt], 0, 0, 0);
        }
      }
    }
#pragma unroll
    for (int mt = 0; mt < 4; mt++) {
#pragma unroll
      for (int ks = 0; ks < 4; ks++) {
        shortx8 af = *(const shortx8*)(kc + mt * 4096 + ks * 1024 + lane * 16);
        S[0][mt] = __builtin_amdgcn_mfma_f32_16x16x32_bf16(af, qf[0][ks], S[0][mt], 0, 0, 0);
        S[1][mt] = __builtin_amdgcn_mfma_f32_16x16x32_bf16(af, qf[1][ks], S[1][mt], 0, 0, 0);
      }
    }
    __builtin_amdgcn_s_setprio(0);
    // barC: all waves' cluster LDS reads done -> VS[nxt] free for V(it+1)
    __asm__ __volatile__("s_barrier" ::: "memory");
    if (it + 1 < JITERS) {
      const unsigned short* vp2 = vbase + (size_t)(it + 1) * 8192;
#pragma unroll
      for (int c4 = 0; c4 < 4; c4++)
        async16(vp2 + c4 * 2048, (char*)VS + nxt * 16384 + c4 * 4096 + w * 1024);
    }

    // ---- max phase (tree, depth 4); overlaps other waves' clusters ----
    float tmax[2];
#pragma unroll
    for (int ig = 0; ig < 2; ig++) {
      float a0 = fmaxf(fmaxf(S[ig][0][0], S[ig][0][1]), fmaxf(S[ig][0][2], S[ig][0][3]));
      float a1 = fmaxf(fmaxf(S[ig][1][0], S[ig][1][1]), fmaxf(S[ig][1][2], S[ig][1][3]));
      float a2 = fmaxf(fmaxf(S[ig][2][0], S[ig][2][1]), fmaxf(S[ig][2][2], S[ig][2][3]));
      float a3 = fmaxf(fmaxf(S[ig][3][0], S[ig][3][1]), fmaxf(S[ig][3][2], S[ig][3][3]));
      float tm = fmaxf(fmaxf(a0, a1), fmaxf(a2, a3));
      tm = fmaxf(tm, __shfl_xor(tm, 16));
      tm = fmaxf(tm, __shfl_xor(tm, 32));
      tmax[ig] = tm;
    }
    // ---- T13 defer-max: only touch m/O when some row grew by > 8 nats ----
    // O-rescale AFTER PV(it-1) accumulated (cluster above) => correct scale ordering.
    float alpha[2] = {1.f, 1.f};
    if (__ballot(tmax[0] > m_i[0] + 8.f || tmax[1] > m_i[1] + 8.f)) {
#pragma unroll
      for (int ig = 0; ig < 2; ig++) {
        float mn = fmaxf(m_i[ig], tmax[ig]);
        alpha[ig] = EXP2F((m_i[ig] - mn) * L2E);
        m_i[ig] = mn;
        float ar[4];
#pragma unroll
        for (int rr = 0; rr < 4; rr++) ar[rr] = __shfl(alpha[ig], quad * 4 + rr);
#pragma unroll
        for (int nt = 0; nt < 8; nt++)
#pragma unroll
          for (int rr = 0; rr < 4; rr++) O[ig][nt][rr] *= ar[rr];
      }
    }
    // ---- exp / sum (tree) / pack into PS; P overwrites S ----
#pragma unroll
    for (int ig = 0; ig < 2; ig++) {
      float nsc = m_i[ig] * L2E;
      float sm[4];
#pragma unroll
      for (int mt = 0; mt < 4; mt++) {
        float p0 = EXP2F(fmaf(S[ig][mt][0], L2E, -nsc));
        float p1 = EXP2F(fmaf(S[ig][mt][1], L2E, -nsc));
        float p2 = EXP2F(fmaf(S[ig][mt][2], L2E, -nsc));
        float p3 = EXP2F(fmaf(S[ig][mt][3], L2E, -nsc));
        S[ig][mt][0] = p0; S[ig][mt][1] = p1; S[ig][mt][2] = p2; S[ig][mt][3] = p3;
        sm[mt] = (p0 + p1) + (p2 + p3);
      }
      float ts = (sm[0] + sm[1]) + (sm[2] + sm[3]);
      ts += __shfl_xor(ts, 16);
      ts += __shfl_xor(ts, 32);
      l_i[ig] = l_i[ig] * alpha[ig] + ts;
      // truncating bf16 pack via v_perm (1 inst/pair)
#pragma unroll
      for (int mt = 0; mt < 4; mt++) {
        unsigned lo = __builtin_amdgcn_perm(__float_as_uint(S[ig][mt][1]),
                                            __float_as_uint(S[ig][mt][0]), 0x07060302u);
        unsigned hi = __builtin_amdgcn_perm(__float_as_uint(S[ig][mt][3]),
                                            __float_as_uint(S[ig][mt][2]), 0x07060302u);
        *(uint2*)(Pw + ig * 2048 + (mt * 2 + (quad >> 1)) * 256 + l16 * 16 + (quad & 1) * 8)
            = make_uint2(lo, hi);
      }
    }
    // pack's lgkm is paid at next iter's cluster top (overlaps K-issue + vmcnt + barrier)
  }
  // epilogue PV(JITERS-1): P(15) in PS, V(15) in VS[(JITERS-1)&1]
  __asm__ __volatile__("s_waitcnt lgkmcnt(0)" ::: "memory");
  {
    const char* vp = (const char*)VS + ((JITERS - 1) & 1) * 16384;
#pragma unroll
    for (int kt = 0; kt < 2; kt++) {
      shortx8 pf0 = *(const shortx8*)(Pw + kt * 1024 + lane * 16);
      shortx8 pf1 = *(const shortx8*)(Pw + 2048 + kt * 1024 + lane * 16);
#pragma unroll
      for (int nt = 0; nt < 8; nt++) {
        shortx8 vfr = *(const shortx8*)(vp + ((nt * 2 + kt) * 64 + lane) * 16);
        O[0][nt] = __builtin_amdgcn_mfma_f32_16x16x32_bf16(pf0, vfr, O[0][nt], 0, 0, 0);
        O[1][nt] = __builtin_amdgcn_mfma_f32_16x16x32_bf16(pf1, vfr, O[1][nt], 0, 0, 0);
      }
    }
  }
  // epilogue: store partial O and (m,l)
#pragma unroll
  for (int ig = 0; ig < 2; ig++) {
    float* Ob = Opart + ((size_t)(sp * 4 + b) * HW + i0 + w * 32 + ig * 16) * 128;
#pragma unroll
    for (int nt = 0; nt < 8; nt++)
#pragma unroll
      for (int rr = 0; rr < 4; rr++)
        Ob[(size_t)(quad * 4 + rr) * 128 + nt * 16 + l16] = O[ig][nt][rr];
  }
  if (quad == 0) {
    float2* mlp = (float2*)ml;
#pragma unroll
    for (int ig = 0; ig < 2; ig++)
      mlp[(size_t)(sp * 4 + b) * HW + i0 + w * 32 + ig * 16 + l16]
          = make_float2(m_i[ig], l_i[ig]);
  }
}

// ---------------- K4: merge split-j partials -> res ------------------------------------
__global__ __launch_bounds__(256) void k_merge(const float* __restrict__ Opart,
    const float* __restrict__ ml, float* __restrict__ res) {
  size_t e = (size_t)blockIdx.x * 256 + threadIdx.x;  // float4 index
  int cq = (int)(e & 31);
  int i = (int)((e >> 5) & 4095);
  int b = (int)(e >> 17);
  const float2* mlp = (const float2*)ml;
  float m[SPLIT], l[SPLIT];
  float M = -1e30f;
#pragma unroll
  for (int s = 0; s < SPLIT; s++) {
    float2 st = mlp[(size_t)(s * 4 + b) * HW + i];
    m[s] = st.x; l[s] = st.y;
    M = fmaxf(M, m[s]);
  }
  float denom = 0.f;
  float wgt[SPLIT];
#pragma unroll
  for (int s = 0; s < SPLIT; s++) {
    float ws_ = EXP2F((m[s] - M) * L2E);
    wgt[s] = ws_;
    denom += l[s] * ws_;
  }
  float inv = 1.f / denom;
  floatx4 acc = {0.f, 0.f, 0.f, 0.f};
#pragma unroll
  for (int s = 0; s < SPLIT; s++) {
    floatx4 v = *(const floatx4*)(Opart + ((size_t)(s * 4 + b) * HW + i) * 128 + cq * 4);
    acc += v * (wgt[s] * inv);
  }
  *(floatx4*)(res + e * 4) = acc;
}

// ---------------- K5: conv4 (fp32) + BN(eval) + residual ------------------------------
__global__ __launch_bounds__(256) void k_out(const float* __restrict__ res,
    const float* __restrict__ w4, const float* __restrict__ gamma,
    const float* __restrict__ beta, const float* __restrict__ rmean,
    const float* __restrict__ rvar, const float* __restrict__ x,
    float* __restrict__ out) {
  __shared__ float wt[16 * 128];
  int bid = blockIdx.x;
  int cot = bid & 15;
  int st = (bid >> 4) & 15;
  int b = bid >> 8;
  int t = threadIdx.x;
  int co0 = cot * 16;
#pragma unroll
  for (int k = 0; k < 8; k++) wt[k * 256 + t] = w4[(size_t)co0 * 128 + k * 256 + t];
  __syncthreads();
  int px = st * 256 + t;
  const float* rb = res + (size_t)b * 524288 + px;
  float acc[16];
#pragma unroll
  for (int r = 0; r < 16; r++) acc[r] = 0.f;
  for (int ci = 0; ci < 128; ci += 4) {
    float xv[4];
#pragma unroll
    for (int kk = 0; kk < 4; kk++) xv[kk] = rb[(size_t)(ci + kk) * HW];
#pragma unroll
    for (int r = 0; r < 16; r++) {
      floatx4 wv = *(const floatx4*)&wt[r * 128 + ci];
#pragma unroll
      for (int kk = 0; kk < 4; kk++) acc[r] += wv[kk] * xv[kk];
    }
  }
  const float* xb = x + ((size_t)b * 256 + co0) * HW + px;
  float* ob = out + ((size_t)b * 256 + co0) * HW + px;
#pragma unroll
  for (int r = 0; r < 16; r++) {
    int co = co0 + r;
    float g = gamma[co] * rsqrtf(rvar[co] + 1e-5f);
    float bb = beta[co] - rmean[co] * g;
    ob[(size_t)r * HW] = acc[r] * g + bb + xb[(size_t)r * HW];
  }
}

extern "C" void kernel_launch(void* const* d_in, const int* in_sizes, int n_in,
                              void* d_out, int out_size, void* d_ws, size_t ws_size,
                              hipStream_t stream) {
  const float* x     = (const float*)d_in[0];
  const float* w1    = (const float*)d_in[1];
  const float* w2    = (const float*)d_in[2];
  const float* w3    = (const float*)d_in[3];
  const float* w4    = (const float*)d_in[4];
  const float* gamma = (const float*)d_in[5];
  const float* beta  = (const float*)d_in[6];
  const float* rmean = (const float*)d_in[7];
  const float* rvar  = (const float*)d_in[8];
  float* out = (float*)d_out;
  char* ws = (char*)d_ws;

  // Opart region (32 MB) overlaps n3 / Xth (dead before k_flash runs)
  size_t off = (size_t)SPLIT * 4 * HW * 128 * 4;             // 32 MB
  float* Opart = (float*)ws;
  unsigned short* n3  = (unsigned short*)ws;                  // 4.2 MB @ 0
  unsigned short* Xth = (unsigned short*)(ws + ((size_t)8 << 20));   // 8.4 MB @ 8M
  unsigned short* Q   = (unsigned short*)(ws + off); off += (size_t)4 * HW * 128 * 2;
  unsigned short* Kt  = (unsigned short*)(ws + off); off += (size_t)4 * HW * 128 * 2;
  unsigned short* VtF = (unsigned short*)(ws + off); off += (size_t)4 * HW * 128 * 2;
  float* ml  = (float*)(ws + off); off += (size_t)SPLIT * 4 * HW * 2 * 4;
  float* res = (float*)(ws + off); off += (size_t)4 * HW * 128 * 4;
  unsigned short* Wh = (unsigned short*)(ws + off); off += (size_t)384 * 256 * 2;
  if (ws_size < off) return;

  k_split   <<<1036, 256, 0, stream>>>(x, w1, w2, w3, Xth, Wh);
  k_projM   <<<768,  256, 0, stream>>>(Xth, Wh, Q, Kt, n3);
  k_layoutVF<<<256,  256, 0, stream>>>(n3, VtF);
  k_flash   <<<512,  256, 0, stream>>>(Q, Kt, VtF, Opart, ml);
  k_merge   <<<2048, 256, 0, stream>>>(Opart, ml, res);
  k_out     <<<1024, 256, 0, stream>>>(res, w4, gamma, beta, rmean, rvar, x, out);
}